// Round 2
// baseline (20052.339 us; speedup 1.0000x reference)
//
#include <hip/hip_runtime.h>
#include <stdint.h>

#define TT    512
#define HID   1024
#define G4    4096
#define INDIM 85
#define NOUT  20670   // 6890*3

typedef unsigned long long u64;
typedef unsigned int u32;

// ---------------------------------------------------------------------------
// Tiled fp32 GEMM: C[M,N] = A[M,K] * B[N,K]^T + bias0 + bias1
// 64x64 tile, BK=16, 256 threads, 4x4 micro-tile per thread. (unchanged)
// ---------------------------------------------------------------------------
__global__ __launch_bounds__(256)
void gemm_nt(const float* __restrict__ A, const float* __restrict__ B,
             const float* __restrict__ bias0, const float* __restrict__ bias1,
             float* __restrict__ C, int M, int N, int K)
{
    __shared__ float As[16 * 68];
    __shared__ float Bs[16 * 68];
    const int tid = threadIdx.x;
    const int tx = tid & 15, ty = tid >> 4;
    const int m0 = blockIdx.y * 64, n0 = blockIdx.x * 64;
    float acc[4][4] = {};
    const int KT = (K + 15) >> 4;

    for (int kt = 0; kt < KT; ++kt) {
        const int k0 = kt << 4;
        __syncthreads();
        for (int l = tid; l < 1024; l += 256) {
            const int mm = l >> 4, kk = l & 15;
            const int kg = k0 + kk;
            As[kk * 68 + mm] = (kg < K) ? A[(size_t)(m0 + mm) * K + kg] : 0.f;
            Bs[kk * 68 + mm] = (kg < K && (n0 + mm) < N)
                                   ? B[(size_t)(n0 + mm) * K + kg] : 0.f;
        }
        __syncthreads();
        #pragma unroll
        for (int kk = 0; kk < 16; ++kk) {
            const float4 av = *(const float4*)&As[kk * 68 + ty * 4];
            const float4 bv = *(const float4*)&Bs[kk * 68 + tx * 4];
            const float a[4] = {av.x, av.y, av.z, av.w};
            const float b[4] = {bv.x, bv.y, bv.z, bv.w};
            #pragma unroll
            for (int i = 0; i < 4; ++i)
                #pragma unroll
                for (int j = 0; j < 4; ++j)
                    acc[i][j] += a[i] * b[j];
        }
    }

    float bj[4];
    #pragma unroll
    for (int j = 0; j < 4; ++j) {
        const int n = n0 + tx * 4 + j;
        float bv = 0.f;
        if (n < N) {
            if (bias0) bv += bias0[n];
            if (bias1) bv += bias1[n];
        }
        bj[j] = bv;
    }
    #pragma unroll
    for (int i = 0; i < 4; ++i) {
        const int m = m0 + ty * 4 + i;
        #pragma unroll
        for (int j = 0; j < 4; ++j) {
            const int n = n0 + tx * 4 + j;
            if (n < N) C[(size_t)m * N + n] = acc[i][j] + bj[j];
        }
    }
}

// ---------------------------------------------------------------------------
// Fused 3-layer pipelined LSTM scan. 768 blocks x 256 threads, 3 blocks/CU.
//   layer = blockIdx>>8, b = blockIdx&255; block owns units u0=4b..4b+3.
//
// ROUND-2 CHANGE (poll-storm fix). Round-1 post-mortem: slot time stayed at
// 8.1us with no spill -> the bottleneck is the h-exchange, and specifically
// POLL TRAFFIC SATURATION: ~200K threads spin-issuing agent-scope atomic
// loads (~1e11/s) saturate the coherence fabric, inflating every exchange op
// from ~0.6us to ~8us. Chunked ih-GEMM (lag-32 pipeline) also regressed and
// is reverted to a fine-grained lag-1 pipeline. Now:
//  * hh weights persistent in regs (64/thread, interleaved cols {ln+64j}).
//  * ih term per-step: W_ih streamed as 16 coalesced float4/thread from L2
//    (slices are L2-resident; loads issued BEFORE the wait -> latency free).
//  * Producers publish tagged quads + ONE release atomicAdd on a group
//    counter (16 counters x 16 blocks per (layer,t), 64B apart).
//  * Consumers: only wave 0 lanes 0..31 poll counters (1/lane, s_sleep
//    backoff) -> ~100x less poll traffic. After ready, ALL threads bulk-read
//    h rows with PLAIN cached uint4 loads (L2-shared across blocks on an
//    XCD), verify tags, and fall back to atomic re-reads on mismatch (so
//    correctness never depends on fence ordering or L2 staleness).
// ---------------------------------------------------------------------------
__device__ __forceinline__ float sig_(float x) { return 1.f / (1.f + expf(-x)); }

__global__ __launch_bounds__(256, 3)
void lstm_fused(const float* __restrict__ xg,
                const float* __restrict__ Whh0,
                const float* __restrict__ Wih1, const float* __restrict__ Whh1,
                const float* __restrict__ bih1, const float* __restrict__ bhh1,
                const float* __restrict__ Wih2, const float* __restrict__ Whh2,
                const float* __restrict__ bih2, const float* __restrict__ bhh2,
                u64* __restrict__ hbuf0, u64* __restrict__ hbuf1,
                u64* __restrict__ hbuf2, u32* __restrict__ cnt,
                float* __restrict__ hs2)
{
    __shared__ float hprev_lds[HID];   // own-layer h(t-1)
    __shared__ float hin_lds[HID];     // lower-layer h(t)   (layers 1,2)
    __shared__ float gsum[4][4];       // [wave/unit][gate]

    const int tid = threadIdx.x;
    const int w = tid >> 6, ln = tid & 63;
    const int layer = blockIdx.x >> 8;
    const int b = blockIdx.x & 255;
    const int u0 = 4 * b;
    const int unit = u0 + w;

    const float* Whh = (layer == 0) ? Whh0 : (layer == 1 ? Whh1 : Whh2);
    const float* Wih = (layer == 1) ? Wih1 : Wih2;                  // unused layer 0
    u64* hbI = (layer == 1) ? hbuf0 : hbuf1;                        // input-h buffer
    u64* hbP = (layer == 0) ? hbuf0 : (layer == 1 ? hbuf1 : hbuf2); // own-layer buffer
    // group counters: cnt[((prodLayer*TT + t)*16 + grp)*16], 64B apart
    u32* cntP = cnt + (size_t)layer * TT * 16 * 16;
    u32* cntI = cnt + (size_t)(layer - 1) * TT * 16 * 16;           // valid layer>0

    // ---- recurrent weights in registers: 4 gates x 16 interleaved cols ----
    float Wv[4][16];
    #pragma unroll
    for (int g = 0; g < 4; ++g) {
        const float* rp = Whh + (size_t)(g * HID + unit) * HID + ln;
        #pragma unroll
        for (int j = 0; j < 16; ++j)
            Wv[g][j] = rp[64 * j];
    }

    // per-(gate,unit) bias for layers 1,2 (layer 0's xg already has biases)
    float add4[4] = {0.f, 0.f, 0.f, 0.f};
    if (w == 0 && ln < 4 && layer > 0) {
        #pragma unroll
        for (int g = 0; g < 4; ++g) {
            const int r = g * HID + u0 + ln;
            add4[g] = (layer == 1) ? (bih1[r] + bhh1[r]) : (bih2[r] + bhh2[r]);
        }
    }

    float c = 0.f;   // cell state in wave-0 lanes 0..3
    for (int t = 0; t < TT; ++t) {
        // ---- prefetch (before any waiting; latency hides under the poll) --
        float4 wih[4][4];
        if (layer > 0) {
            #pragma unroll
            for (int g = 0; g < 4; ++g) {
                const float* rp = Wih + (size_t)(g * HID + unit) * HID + 4 * ln;
                #pragma unroll
                for (int jj = 0; jj < 4; ++jj)
                    wih[g][jj] = *(const float4*)(rp + 256 * jj);
            }
        }
        float xg4[4];
        if (layer == 0 && w == 0 && ln < 4) {
            #pragma unroll
            for (int g = 0; g < 4; ++g)
                xg4[g] = xg[(size_t)t * G4 + g * HID + u0 + ln];
        }

        // ---- wave 0 polls ready-counters; everyone else parks at barrier --
        if (w == 0) {
            const u32* caddr = nullptr;
            bool need = false;
            if (ln < 16) {
                if (t > 0) { need = true; caddr = cntP + ((size_t)(t - 1) * 16 + ln) * 16; }
            } else if (ln < 32) {
                if (layer > 0) { need = true; caddr = cntI + ((size_t)t * 16 + (ln - 16)) * 16; }
            }
            bool done = !need;
            int guard = 0;
            while (!__all(done)) {
                if (!done) {
                    const u32 v = __hip_atomic_load(caddr, __ATOMIC_RELAXED,
                                                    __HIP_MEMORY_SCOPE_AGENT);
                    done = (v >= 16);
                }
                if (++guard > (1 << 22)) break;   // anti-hang bailout
                if (!__all(done)) __builtin_amdgcn_s_sleep(2);
            }
        }
        __syncthreads();   // (0) rows ready

        // ---- bulk h read: plain cached loads + tag verify + LDS stage -----
        const int p4 = 4 * ((tid + b) & 255);
        if (t == 0) {
            *(float4*)&hprev_lds[p4] = make_float4(0.f, 0.f, 0.f, 0.f);
        } else {
            const u64* pp = hbP + (size_t)(t - 1) * HID + p4;
            uint4 A = *(const uint4*)pp;          // words 0,1 (lo,hi,lo,hi)
            uint4 B2 = *(const uint4*)(pp + 2);   // words 2,3
            const u32 tag = (u32)t;
            if (!(A.y == tag && A.w == tag && B2.y == tag && B2.w == tag)) {
                int guard = 0;                    // fallback: atomic re-read
                for (;;) {
                    const u64 q0 = __hip_atomic_load(pp + 0, __ATOMIC_RELAXED, __HIP_MEMORY_SCOPE_AGENT);
                    const u64 q1 = __hip_atomic_load(pp + 1, __ATOMIC_RELAXED, __HIP_MEMORY_SCOPE_AGENT);
                    const u64 q2 = __hip_atomic_load(pp + 2, __ATOMIC_RELAXED, __HIP_MEMORY_SCOPE_AGENT);
                    const u64 q3 = __hip_atomic_load(pp + 3, __ATOMIC_RELAXED, __HIP_MEMORY_SCOPE_AGENT);
                    if ((q0 >> 32) == tag && (q1 >> 32) == tag &&
                        (q2 >> 32) == tag && (q3 >> 32) == tag) {
                        A.x = (u32)q0; A.z = (u32)q1; B2.x = (u32)q2; B2.z = (u32)q3;
                        break;
                    }
                    if (++guard > (1 << 22)) break;
                    __builtin_amdgcn_s_sleep(1);
                }
            }
            *(float4*)&hprev_lds[p4] = make_float4(
                __uint_as_float(A.x), __uint_as_float(A.z),
                __uint_as_float(B2.x), __uint_as_float(B2.z));
        }
        if (layer > 0) {
            const u64* pi = hbI + (size_t)t * HID + p4;
            uint4 A = *(const uint4*)pi;
            uint4 B2 = *(const uint4*)(pi + 2);
            const u32 tag = (u32)(t + 1);
            if (!(A.y == tag && A.w == tag && B2.y == tag && B2.w == tag)) {
                int guard = 0;
                for (;;) {
                    const u64 q0 = __hip_atomic_load(pi + 0, __ATOMIC_RELAXED, __HIP_MEMORY_SCOPE_AGENT);
                    const u64 q1 = __hip_atomic_load(pi + 1, __ATOMIC_RELAXED, __HIP_MEMORY_SCOPE_AGENT);
                    const u64 q2 = __hip_atomic_load(pi + 2, __ATOMIC_RELAXED, __HIP_MEMORY_SCOPE_AGENT);
                    const u64 q3 = __hip_atomic_load(pi + 3, __ATOMIC_RELAXED, __HIP_MEMORY_SCOPE_AGENT);
                    if ((q0 >> 32) == tag && (q1 >> 32) == tag &&
                        (q2 >> 32) == tag && (q3 >> 32) == tag) {
                        A.x = (u32)q0; A.z = (u32)q1; B2.x = (u32)q2; B2.z = (u32)q3;
                        break;
                    }
                    if (++guard > (1 << 22)) break;
                    __builtin_amdgcn_s_sleep(1);
                }
            }
            *(float4*)&hin_lds[p4] = make_float4(
                __uint_as_float(A.x), __uint_as_float(A.z),
                __uint_as_float(B2.x), __uint_as_float(B2.z));
        }
        __syncthreads();   // (1) h vectors staged

        // ---- matvecs: hh (reg weights) + ih (streamed weights) ------------
        float a0 = 0.f, a1 = 0.f, a2 = 0.f, a3 = 0.f;
        #pragma unroll
        for (int j = 0; j < 16; ++j) {
            const float h = hprev_lds[ln + 64 * j];
            a0 += Wv[0][j] * h;
            a1 += Wv[1][j] * h;
            a2 += Wv[2][j] * h;
            a3 += Wv[3][j] * h;
        }
        if (layer > 0) {
            #pragma unroll
            for (int jj = 0; jj < 4; ++jj) {
                const float4 h4 = *(const float4*)&hin_lds[4 * ln + 256 * jj];
                a0 += wih[0][jj].x * h4.x + wih[0][jj].y * h4.y + wih[0][jj].z * h4.z + wih[0][jj].w * h4.w;
                a1 += wih[1][jj].x * h4.x + wih[1][jj].y * h4.y + wih[1][jj].z * h4.z + wih[1][jj].w * h4.w;
                a2 += wih[2][jj].x * h4.x + wih[2][jj].y * h4.y + wih[2][jj].z * h4.z + wih[2][jj].w * h4.w;
                a3 += wih[3][jj].x * h4.x + wih[3][jj].y * h4.y + wih[3][jj].z * h4.z + wih[3][jj].w * h4.w;
            }
        }
        // 64-lane butterfly: full 1024-col dot per gate (ih+hh summed)
        #pragma unroll
        for (int off = 1; off < 64; off <<= 1) {
            a0 += __shfl_xor(a0, off, 64);
            a1 += __shfl_xor(a1, off, 64);
            a2 += __shfl_xor(a2, off, 64);
            a3 += __shfl_xor(a3, off, 64);
        }
        if (ln == 0) {
            gsum[w][0] = a0; gsum[w][1] = a1; gsum[w][2] = a2; gsum[w][3] = a3;
        }
        __syncthreads();   // (2) gate sums exchanged; LDS safe next iter

        // ---- wave 0 lanes 0..3: elementwise + publish + counter release ---
        if (w == 0 && ln < 4) {
            const float b0 = (layer == 0) ? xg4[0] : add4[0];
            const float b1 = (layer == 0) ? xg4[1] : add4[1];
            const float b2 = (layer == 0) ? xg4[2] : add4[2];
            const float b3 = (layer == 0) ? xg4[3] : add4[3];
            const float i_ = sig_(gsum[ln][0] + b0);
            const float f_ = sig_(gsum[ln][1] + b1);
            const float g_ = tanhf(gsum[ln][2] + b2);
            const float o_ = sig_(gsum[ln][3] + b3);
            c = f_ * c + i_ * g_;
            const float h = o_ * tanhf(c);
            if (layer == 2) hs2[(size_t)t * HID + u0 + ln] = h;
            const u64 pv = (((u64)(unsigned)(t + 1)) << 32) |
                           (u64)__float_as_uint(h);
            __hip_atomic_store(hbP + (size_t)t * HID + u0 + ln, pv,
                               __ATOMIC_RELAXED, __HIP_MEMORY_SCOPE_AGENT);
            if (ln == 0) {
                // RELEASE: drains the wave's quad stores (vmcnt) before the add
                __hip_atomic_fetch_add(cntP + ((size_t)t * 16 + (b >> 4)) * 16, 1u,
                                       __ATOMIC_RELEASE, __HIP_MEMORY_SCOPE_AGENT);
            }
        }
    }
}

// ---------------------------------------------------------------------------
extern "C" void kernel_launch(void* const* d_in, const int* in_sizes, int n_in,
                              void* d_out, int out_size, void* d_ws, size_t ws_size,
                              hipStream_t stream)
{
    (void)in_sizes; (void)n_in; (void)out_size; (void)ws_size;

    const float* pose = (const float*)d_in[0];
    const float* Wih0 = (const float*)d_in[1];
    const float* Whh0 = (const float*)d_in[2];
    const float* bih0 = (const float*)d_in[3];
    const float* bhh0 = (const float*)d_in[4];
    const float* Wih1 = (const float*)d_in[5];
    const float* Whh1 = (const float*)d_in[6];
    const float* bih1 = (const float*)d_in[7];
    const float* bhh1 = (const float*)d_in[8];
    const float* Wih2 = (const float*)d_in[9];
    const float* Whh2 = (const float*)d_in[10];
    const float* bih2 = (const float*)d_in[11];
    const float* bhh2 = (const float*)d_in[12];
    const float* Wout = (const float*)d_in[13];
    float* out = (float*)d_out;

    // Workspace: hbuf0|hbuf1|hbuf2 (3 x 4 MB) | cnt (1.5 MB) | xg (8 MB) | hs2 (2 MB)
    char* ws = (char*)d_ws;
    const size_t HB = (size_t)TT * HID * sizeof(u64);
    const size_t CNT = (size_t)3 * TT * 16 * 16 * sizeof(u32);
    u64* hbuf0 = (u64*)ws;
    u64* hbuf1 = (u64*)(ws + HB);
    u64* hbuf2 = (u64*)(ws + 2 * HB);
    u32* cnt   = (u32*)(ws + 3 * HB);
    float* xg  = (float*)(ws + 3 * HB + CNT);
    float* hs2 = (float*)(ws + 3 * HB + CNT + (size_t)TT * G4 * sizeof(float));

    hipMemsetAsync(hbuf0, 0, 3 * HB + CNT, stream);

    const dim3 blk(256);
    // layer-0 x-gates: [512,85] x [85,4096]^T (+ both biases)
    gemm_nt<<<dim3(G4 / 64, TT / 64), blk, 0, stream>>>(
        pose, Wih0, bih0, bhh0, xg, TT, G4, INDIM);
    // fused pipelined 3-layer scan
    lstm_fused<<<dim3(768), blk, 0, stream>>>(
        xg, Whh0, Wih1, Whh1, bih1, bhh1, Wih2, Whh2, bih2, bhh2,
        hbuf0, hbuf1, hbuf2, cnt, hs2);
    // output projection: [512,1024] x [1024,20670]^T
    gemm_nt<<<dim3((NOUT + 63) / 64, TT / 64), blk, 0, stream>>>(
        hs2, Wout, nullptr, nullptr, out, TT, NOUT, HID);
}

// Round 5
// 4724.543 us; speedup vs baseline: 4.2443x; 4.2443x over previous
//
#include <hip/hip_runtime.h>
#include <stdint.h>

#define TT    512
#define HID   1024
#define G4    4096
#define INDIM 85
#define NOUT  20670   // 6890*3

typedef unsigned long long u64;
typedef unsigned int u32;

// ---------------------------------------------------------------------------
// Tiled fp32 GEMM: C[M,N] = A[M,K] * B[N,K]^T + bias0 + bias1
// 64x64 tile, BK=16, 256 threads, 4x4 micro-tile per thread. (unchanged)
// ---------------------------------------------------------------------------
__global__ __launch_bounds__(256)
void gemm_nt(const float* __restrict__ A, const float* __restrict__ B,
             const float* __restrict__ bias0, const float* __restrict__ bias1,
             float* __restrict__ C, int M, int N, int K)
{
    __shared__ float As[16 * 68];
    __shared__ float Bs[16 * 68];
    const int tid = threadIdx.x;
    const int tx = tid & 15, ty = tid >> 4;
    const int m0 = blockIdx.y * 64, n0 = blockIdx.x * 64;
    float acc[4][4] = {};
    const int KT = (K + 15) >> 4;

    for (int kt = 0; kt < KT; ++kt) {
        const int k0 = kt << 4;
        __syncthreads();
        for (int l = tid; l < 1024; l += 256) {
            const int mm = l >> 4, kk = l & 15;
            const int kg = k0 + kk;
            As[kk * 68 + mm] = (kg < K) ? A[(size_t)(m0 + mm) * K + kg] : 0.f;
            Bs[kk * 68 + mm] = (kg < K && (n0 + mm) < N)
                                   ? B[(size_t)(n0 + mm) * K + kg] : 0.f;
        }
        __syncthreads();
        #pragma unroll
        for (int kk = 0; kk < 16; ++kk) {
            const float4 av = *(const float4*)&As[kk * 68 + ty * 4];
            const float4 bv = *(const float4*)&Bs[kk * 68 + tx * 4];
            const float a[4] = {av.x, av.y, av.z, av.w};
            const float b[4] = {bv.x, bv.y, bv.z, bv.w};
            #pragma unroll
            for (int i = 0; i < 4; ++i)
                #pragma unroll
                for (int j = 0; j < 4; ++j)
                    acc[i][j] += a[i] * b[j];
        }
    }

    float bj[4];
    #pragma unroll
    for (int j = 0; j < 4; ++j) {
        const int n = n0 + tx * 4 + j;
        float bv = 0.f;
        if (n < N) {
            if (bias0) bv += bias0[n];
            if (bias1) bv += bias1[n];
        }
        bj[j] = bv;
    }
    #pragma unroll
    for (int i = 0; i < 4; ++i) {
        const int m = m0 + ty * 4 + i;
        #pragma unroll
        for (int j = 0; j < 4; ++j) {
            const int n = n0 + tx * 4 + j;
            if (n < N) C[(size_t)m * N + n] = acc[i][j] + bj[j];
        }
    }
}

// ---------------------------------------------------------------------------
// Fused 3-layer pipelined LSTM scan. 768 blocks x 256 threads, 3 blocks/CU.
//   layer = blockIdx>>8, b = blockIdx&255; block owns units u0=4b..4b+3.
//
// ROUND-5: fix R4's compile error (s_sleep needs a LITERAL operand -> the
// exp-backoff is now a constant-arg switch). Same experiment as R3/R4:
//
// THEORY E (being tested): R0/R1 sat at 8.1us/step regardless of poll
// VOLUME -> not fabric bandwidth; suspect same-line agent-atomic poll
// serialization at the owning L3 slice (~512-1024 pollers/line). Fast path:
// each thread first reads its quad with two cached uint4 loads and checks
// embedded tags (tag+payload share one u64 -> no tear; a line with tag t can
// only hold the true published h: the only writers are memset(0) and the
// single tagged store; kernel-launch acquire invalidates L2 so no
// cross-dispatch staleness). Hit -> zero atomics for this row. Miss -> the
// line may be stale in this XCD's L2 -> unchanged R0 atomic poll (atomics
// bypass L2). Every fast-path hit removes a poller from the hot line's
// queue, shortening the slow path too. Hardening: guard 1<<18 (bailout in
// seconds, not minutes, if anything wedges); capped exp backoff cuts each
// poller's steady-state atomic rate 4-8x.
// ---------------------------------------------------------------------------
__device__ __forceinline__ float sig_(float x) { return 1.f / (1.f + expf(-x)); }

__device__ __forceinline__ void sleep_k_(int k)
{
    switch (k) {
        case 0:  __builtin_amdgcn_s_sleep(1);  break;   // ~64 cy
        case 1:  __builtin_amdgcn_s_sleep(2);  break;
        case 2:  __builtin_amdgcn_s_sleep(4);  break;
        case 3:  __builtin_amdgcn_s_sleep(8);  break;
        default: __builtin_amdgcn_s_sleep(16); break;   // ~1024 cy cap
    }
}

__global__ __launch_bounds__(256, 3)
void lstm_fused(const float* __restrict__ xg,
                const float* __restrict__ Whh0,
                const float* __restrict__ Wih1, const float* __restrict__ Whh1,
                const float* __restrict__ bih1, const float* __restrict__ bhh1,
                const float* __restrict__ Wih2, const float* __restrict__ Whh2,
                const float* __restrict__ bih2, const float* __restrict__ bhh2,
                u64* __restrict__ hbuf0, u64* __restrict__ hbuf1,
                u64* __restrict__ hbuf2, float* __restrict__ hs2)
{
    __shared__ float hin_lds[HID];
    __shared__ float hprev_lds[HID];
    __shared__ float gsum[4][4];   // [wave/unit][gate]

    const int tid = threadIdx.x;
    const int w = tid >> 6, ln = tid & 63, q = ln & 31;
    const bool inHalf = (ln < 32);
    const int layer = blockIdx.x >> 8;
    const int b = blockIdx.x & 255;
    const int u0 = 4 * b;
    const int unit = u0 + w;

    const float* Wih = (layer == 1) ? Wih1 : Wih2;                 // unused for layer 0
    const float* Whh = (layer == 0) ? Whh0 : (layer == 1 ? Whh1 : Whh2);
    u64* hbI = (layer == 1) ? hbuf0 : hbuf1;                        // input-h buffer (layers 1,2)
    u64* hbP = (layer == 0) ? hbuf0 : (layer == 1 ? hbuf1 : hbuf2); // own-layer buffer

    // ---- stage weights: 4 gate-rows x 32 cols of one matrix per lane ----
    float4 Wv[4][8];
    if (layer == 0 && inHalf) {
        #pragma unroll
        for (int g = 0; g < 4; ++g)
            #pragma unroll
            for (int j = 0; j < 8; ++j)
                Wv[g][j] = make_float4(0.f, 0.f, 0.f, 0.f);
    } else {
        const float* M = inHalf ? Wih : Whh;
        #pragma unroll
        for (int g = 0; g < 4; ++g) {
            const float* rp = M + (size_t)(g * HID + unit) * HID + 4 * q;
            #pragma unroll
            for (int j = 0; j < 8; ++j)
                Wv[g][j] = *(const float4*)(rp + 128 * j);
        }
    }

    // per-gate additive term: WAVE 0 LANES 0..3, lane ln handles unit u0+ln.
    float add4[4] = {0.f, 0.f, 0.f, 0.f};
    if (w == 0 && ln < 4 && layer > 0) {
        #pragma unroll
        for (int g = 0; g < 4; ++g) {
            const int r = g * HID + u0 + ln;
            add4[g] = (layer == 1) ? (bih1[r] + bhh1[r]) : (bih2[r] + bhh2[r]);
        }
    }

    if (layer == 0) {   // W_ih half unused: keep hin_lds at exact zeros
        const int p4z = 4 * ((tid + b) & 255);
        *(float4*)&hin_lds[p4z] = make_float4(0.f, 0.f, 0.f, 0.f);
    }

    float c = 0.f;   // cell state in wave-0 lanes 0..3
    for (int t = 0; t < TT; ++t) {
        if (layer == 0 && w == 0 && ln < 4) {   // x-gates prefetch (pre-poll)
            #pragma unroll
            for (int g = 0; g < 4; ++g)
                add4[g] = xg[(size_t)t * G4 + g * HID + u0 + ln];
        }

        // ---- acquire h vectors (block-rotated unit assignment) ----
        const int p4 = 4 * ((tid + b) & 255);
        bool doneP = (t == 0), doneI = (layer == 0);
        u64 vp0 = 0, vp1 = 0, vp2 = 0, vp3 = 0;
        u64 vi0 = 0, vi1 = 0, vi2 = 0, vi3 = 0;
        const u32 tP32 = (u32)t;                    // hbP[t-1] carries tag t
        const u32 tI32 = (u32)(t + 1);              // hbI[t]   carries tag t+1
        const u64 tagP = (u64)tP32;
        const u64 tagI = (u64)tI32;
        const u64* pp = hbP + (size_t)(t - 1) * HID + p4;
        const u64* pi = hbI + (size_t)t * HID + p4;

        // ---- FAST PATH: one-shot plain cached reads, tag-verified ----
        if (!doneP) {
            const uint4 a  = *(const uint4*)(pp);       // quads 0,1
            const uint4 b2 = *(const uint4*)(pp + 2);   // quads 2,3
            if (a.y == tP32 && a.w == tP32 && b2.y == tP32 && b2.w == tP32) {
                vp0 = ((u64)a.y  << 32) | a.x;  vp1 = ((u64)a.w  << 32) | a.z;
                vp2 = ((u64)b2.y << 32) | b2.x; vp3 = ((u64)b2.w << 32) | b2.z;
                doneP = true;
            }
        }
        if (!doneI) {
            const uint4 a  = *(const uint4*)(pi);
            const uint4 b2 = *(const uint4*)(pi + 2);
            if (a.y == tI32 && a.w == tI32 && b2.y == tI32 && b2.w == tI32) {
                vi0 = ((u64)a.y  << 32) | a.x;  vi1 = ((u64)a.w  << 32) | a.z;
                vi2 = ((u64)b2.y << 32) | b2.x; vi3 = ((u64)b2.w << 32) | b2.z;
                doneI = true;
            }
        }

        // ---- SLOW PATH: R0 atomic poll (bypasses stale L2) + exp backoff --
        if (!(doneP && doneI)) {
            int guard = 0, k = 0;
            for (;;) {
                if (!doneP) {
                    vp0 = __hip_atomic_load(pp + 0, __ATOMIC_RELAXED, __HIP_MEMORY_SCOPE_AGENT);
                    if ((vp0 >> 32) == tagP) {   // sentinel hit: quad published together
                        vp1 = __hip_atomic_load(pp + 1, __ATOMIC_RELAXED, __HIP_MEMORY_SCOPE_AGENT);
                        vp2 = __hip_atomic_load(pp + 2, __ATOMIC_RELAXED, __HIP_MEMORY_SCOPE_AGENT);
                        vp3 = __hip_atomic_load(pp + 3, __ATOMIC_RELAXED, __HIP_MEMORY_SCOPE_AGENT);
                        doneP = (vp1 >> 32) == tagP && (vp2 >> 32) == tagP &&
                                (vp3 >> 32) == tagP;
                    }
                }
                if (!doneI) {
                    vi0 = __hip_atomic_load(pi + 0, __ATOMIC_RELAXED, __HIP_MEMORY_SCOPE_AGENT);
                    if ((vi0 >> 32) == tagI) {
                        vi1 = __hip_atomic_load(pi + 1, __ATOMIC_RELAXED, __HIP_MEMORY_SCOPE_AGENT);
                        vi2 = __hip_atomic_load(pi + 2, __ATOMIC_RELAXED, __HIP_MEMORY_SCOPE_AGENT);
                        vi3 = __hip_atomic_load(pi + 3, __ATOMIC_RELAXED, __HIP_MEMORY_SCOPE_AGENT);
                        doneI = (vi1 >> 32) == tagI && (vi2 >> 32) == tagI &&
                                (vi3 >> 32) == tagI;
                    }
                }
                if (doneP && doneI) break;
                if (++guard > (1 << 18)) break;   // anti-hang bailout (unreached when healthy)
                sleep_k_(k);                      // capped exp backoff: 64..1024cy
                if (k < 4) ++k;
            }
        }

        if (t == 0)
            *(float4*)&hprev_lds[p4] = make_float4(0.f, 0.f, 0.f, 0.f);
        else
            *(float4*)&hprev_lds[p4] = make_float4(
                __uint_as_float((unsigned)vp0), __uint_as_float((unsigned)vp1),
                __uint_as_float((unsigned)vp2), __uint_as_float((unsigned)vp3));
        if (layer > 0)
            *(float4*)&hin_lds[p4] = make_float4(
                __uint_as_float((unsigned)vi0), __uint_as_float((unsigned)vi1),
                __uint_as_float((unsigned)vi2), __uint_as_float((unsigned)vi3));
        __syncthreads();   // (1) h vectors staged

        // ---- matvec: 4 gate rows x 32 cols, weights in regs, h from LDS ----
        const float* hsrc = (inHalf ? hin_lds : hprev_lds) + 4 * q;
        float a0 = 0.f, a1 = 0.f, a2 = 0.f, a3 = 0.f;
        #pragma unroll
        for (int j = 0; j < 8; ++j) {
            const float4 hv = *(const float4*)(hsrc + 128 * j);
            a0 += Wv[0][j].x * hv.x + Wv[0][j].y * hv.y + Wv[0][j].z * hv.z + Wv[0][j].w * hv.w;
            a1 += Wv[1][j].x * hv.x + Wv[1][j].y * hv.y + Wv[1][j].z * hv.z + Wv[1][j].w * hv.w;
            a2 += Wv[2][j].x * hv.x + Wv[2][j].y * hv.y + Wv[2][j].z * hv.z + Wv[2][j].w * hv.w;
            a3 += Wv[3][j].x * hv.x + Wv[3][j].y * hv.y + Wv[3][j].z * hv.z + Wv[3][j].w * hv.w;
        }
        // 64-lane butterfly: sums ih-partials (lanes<32) + hh-partials (>=32)
        #pragma unroll
        for (int off = 1; off < 64; off <<= 1) {
            a0 += __shfl_xor(a0, off, 64);
            a1 += __shfl_xor(a1, off, 64);
            a2 += __shfl_xor(a2, off, 64);
            a3 += __shfl_xor(a3, off, 64);
        }
        if (ln == 0) {
            gsum[w][0] = a0; gsum[w][1] = a1; gsum[w][2] = a2; gsum[w][3] = a3;
        }
        __syncthreads();   // (2) gate sums exchanged; LDS safe to overwrite next iter

        // ---- wave 0 lanes 0..3: elementwise + COALESCED quad publish ----
        if (w == 0 && ln < 4) {
            const float i_ = sig_(gsum[ln][0] + add4[0]);
            const float f_ = sig_(gsum[ln][1] + add4[1]);
            const float g_ = tanhf(gsum[ln][2] + add4[2]);
            const float o_ = sig_(gsum[ln][3] + add4[3]);
            c = f_ * c + i_ * g_;
            const float h = o_ * tanhf(c);
            if (layer == 2) hs2[(size_t)t * HID + u0 + ln] = h;
            const u64 pv = (((u64)(unsigned)(t + 1)) << 32) |
                           (u64)__float_as_uint(h);
            __hip_atomic_store(hbP + (size_t)t * HID + u0 + ln, pv,
                               __ATOMIC_RELAXED, __HIP_MEMORY_SCOPE_AGENT);
        }
        // Next iteration's poll gates every consumer on this publish; gsum is
        // rewritten only after the next barrier(1)+matvec, so no extra barrier.
    }
}

// ---------------------------------------------------------------------------
extern "C" void kernel_launch(void* const* d_in, const int* in_sizes, int n_in,
                              void* d_out, int out_size, void* d_ws, size_t ws_size,
                              hipStream_t stream)
{
    (void)in_sizes; (void)n_in; (void)out_size; (void)ws_size;

    const float* pose = (const float*)d_in[0];
    const float* Wih0 = (const float*)d_in[1];
    const float* Whh0 = (const float*)d_in[2];
    const float* bih0 = (const float*)d_in[3];
    const float* bhh0 = (const float*)d_in[4];
    const float* Wih1 = (const float*)d_in[5];
    const float* Whh1 = (const float*)d_in[6];
    const float* bih1 = (const float*)d_in[7];
    const float* bhh1 = (const float*)d_in[8];
    const float* Wih2 = (const float*)d_in[9];
    const float* Whh2 = (const float*)d_in[10];
    const float* bih2 = (const float*)d_in[11];
    const float* bhh2 = (const float*)d_in[12];
    const float* Wout = (const float*)d_in[13];
    float* out = (float*)d_out;

    // Workspace: hbuf0|hbuf1|hbuf2 (3 x 4 MB tagged u64) | xg (8 MB) | hs2 (2 MB)
    char* ws = (char*)d_ws;
    const size_t HB = (size_t)TT * HID * sizeof(u64);
    u64* hbuf0 = (u64*)ws;
    u64* hbuf1 = (u64*)(ws + HB);
    u64* hbuf2 = (u64*)(ws + 2 * HB);
    float* xg  = (float*)(ws + 3 * HB);
    float* hs2 = (float*)(ws + 3 * HB + (size_t)TT * G4 * sizeof(float));

    (void)hipMemsetAsync(hbuf0, 0, 3 * HB, stream);

    const dim3 blk(256);
    // layer-0 x-gates: [512,85] x [85,4096]^T (+ both biases)
    gemm_nt<<<dim3(G4 / 64, TT / 64), blk, 0, stream>>>(
        pose, Wih0, bih0, bhh0, xg, TT, G4, INDIM);
    // fused pipelined 3-layer scan
    lstm_fused<<<dim3(768), blk, 0, stream>>>(
        xg, Whh0, Wih1, Whh1, bih1, bhh1, Wih2, Whh2, bih2, bhh2,
        hbuf0, hbuf1, hbuf2, hs2);
    // output projection: [512,1024] x [1024,20670]^T
    gemm_nt<<<dim3((NOUT + 63) / 64, TT / 64), blk, 0, stream>>>(
        hs2, Wout, nullptr, nullptr, out, TT, NOUT, HID);
}